// Round 2
// baseline (799.906 us; speedup 1.0000x reference)
//
#include <hip/hip_runtime.h>

#define NN 65536
#define BB 64
#define HH 1024
#define MM 64
#define RR 4

__device__ __forceinline__ float waveReduceSum(float v) {
#pragma unroll
  for (int off = 32; off > 0; off >>= 1) v += __shfl_xor(v, off, 64);
  return v;
}

// fast pow for positive base: wt^p = exp(p * log(wt))
__device__ __forceinline__ float fastPow(float wt, float p) {
  return __expf(p * __logf(wt));
}

// ---------------------------------------------------------------------------
// K1: per-batch head parameters from h_t.
// grid 64 (one block per b), block 256.
// wave0: k (->kn), wave1: e, wave2: a, wave3: beta/g/gamma/shift (wave-wide dots)
// block 0 additionally zero-inits RS0/RS1/GS accumulators.
// ---------------------------------------------------------------------------
__global__ __launch_bounds__(256) void prep_kernel(
    const float* __restrict__ h_t,
    const float* __restrict__ key_w, const float* __restrict__ key_b,
    const float* __restrict__ beta_w, const float* __restrict__ beta_b,
    const float* __restrict__ gate_w, const float* __restrict__ gate_b,
    const float* __restrict__ shift_w, const float* __restrict__ shift_b,
    const float* __restrict__ gamma_w, const float* __restrict__ gamma_b,
    const float* __restrict__ erase_w, const float* __restrict__ erase_b,
    const float* __restrict__ add_w, const float* __restrict__ add_b,
    float* __restrict__ kn, float* __restrict__ e_v, float* __restrict__ a_v,
    float* __restrict__ beta, float* __restrict__ g, float* __restrict__ gamma_,
    float* __restrict__ s,
    float* __restrict__ RS0, float* __restrict__ RS1, float* __restrict__ GS)
{
  const int b = blockIdx.x;
  const int t = threadIdx.x;
  __shared__ float h_sh[HH];
  __shared__ float k_sh[64];
#pragma unroll
  for (int i = 0; i < 4; i++) h_sh[t + 256 * i] = h_t[b * HH + t + 256 * i];
  __syncthreads();

  if (t < 64) {
    float d = 0.f;
#pragma unroll 8
    for (int hh = 0; hh < HH; hh++) d += h_sh[hh] * key_w[hh * 64 + t];
    k_sh[t] = fminf(fmaxf(d + key_b[t], 0.f), 1.f);
  } else if (t < 128) {
    const int m = t - 64;
    float d = 0.f;
#pragma unroll 8
    for (int hh = 0; hh < HH; hh++) d += h_sh[hh] * erase_w[hh * 64 + m];
    e_v[b * 64 + m] = fminf(fmaxf(d + erase_b[m], 0.f), 1.f);
  } else if (t < 192) {
    const int m = t - 128;
    float d = 0.f;
#pragma unroll 8
    for (int hh = 0; hh < HH; hh++) d += h_sh[hh] * add_w[hh * 64 + m];
    a_v[b * 64 + m] = fminf(fmaxf(d + add_b[m], 0.f), 1.f);  // relu then clip01 == clip01
  } else {
    // wave 3: six length-1024 dots, each computed wave-wide then reduced
    const int lane = t - 192;
    float outs[6];
#pragma unroll 1
    for (int o = 0; o < 6; o++) {
      float d = 0.f;
      if (o < 3) {
        const float* W = (o == 0) ? beta_w : ((o == 1) ? gate_w : gamma_w);
        for (int hh = lane; hh < HH; hh += 64) d += h_sh[hh] * W[hh];
      } else {
        const int j = o - 3;
        for (int hh = lane; hh < HH; hh += 64) d += h_sh[hh] * shift_w[hh * 3 + j];
      }
      outs[o] = waveReduceSum(d);
    }
    if (lane == 0) {
      beta[b]  = fmaxf(outs[0] + beta_b[0], 0.f);
      g[b]     = fminf(fmaxf(outs[1] + gate_b[0], 0.f), 1.f);
      gamma_[b] = 1.0f + fmaxf(outs[2] + gamma_b[0], 0.f);
      const float l0 = outs[3] + shift_b[0];
      const float l1 = outs[4] + shift_b[1];
      const float l2 = outs[5] + shift_b[2];
      const float mx = fmaxf(l0, fmaxf(l1, l2));
      const float e0 = __expf(l0 - mx), e1 = __expf(l1 - mx), e2 = __expf(l2 - mx);
      const float inv = 1.f / (e0 + e1 + e2);
      s[b * 3 + 0] = e0 * inv; s[b * 3 + 1] = e1 * inv; s[b * 3 + 2] = e2 * inv;
    }
  }
  __syncthreads();
  if (t < 64) {
    float ss = 0.f;
    for (int j = 0; j < 64; j++) ss += k_sh[j] * k_sh[j];
    kn[b * 64 + t] = k_sh[t] / (sqrtf(ss) + 1e-8f);
  }
  if (b == 0) {
    if (t < 64) { RS0[t] = 0.f; RS1[t] = 0.f; }
    if (t < 5) GS[t] = 0.f;
  }
}

// ---------------------------------------------------------------------------
// K2 / K5: content addressing against a memory matrix.
// E[b,n] = exp(beta_b * (kn_b . mem_n) / (||mem_n|| + 1e-8)), RS[b] += row sums.
// grid 256, block 256 (thread per n). bank==nullptr -> mem used directly (m1).
// ---------------------------------------------------------------------------
__global__ __launch_bounds__(256) void content_kernel(
    const float* __restrict__ mem, const int* __restrict__ bank,
    const float* __restrict__ kn, const float* __restrict__ beta,
    float* __restrict__ E, float* __restrict__ RS)
{
  const float* Mrow = mem + (bank ? ((size_t)(*bank) * (size_t)NN * MM) : (size_t)0);
  const int n = blockIdx.x * 256 + threadIdx.x;
  float4 row[16];
  const float4* rp = (const float4*)(Mrow + (size_t)n * MM);
#pragma unroll
  for (int q = 0; q < 16; q++) row[q] = rp[q];
  float ss = 0.f;
#pragma unroll
  for (int q = 0; q < 16; q++)
    ss += row[q].x * row[q].x + row[q].y * row[q].y + row[q].z * row[q].z + row[q].w * row[q].w;
  const float rinv = 1.0f / (sqrtf(ss) + 1e-8f);

  __shared__ float acc[64][4];
  const int wid = threadIdx.x >> 6;
  const int lane = threadIdx.x & 63;
  for (int b = 0; b < 64; b++) {
    const float4* kp = (const float4*)(kn + b * 64);
    float dot = 0.f;
#pragma unroll
    for (int q = 0; q < 16; q++) {
      const float4 kq = kp[q];
      dot += kq.x * row[q].x + kq.y * row[q].y + kq.z * row[q].z + kq.w * row[q].w;
    }
    const float e = __expf(beta[b] * dot * rinv);
    E[(size_t)b * NN + n] = e;
    const float r = waveReduceSum(e);
    if (lane == 0) acc[b][wid] = r;
  }
  __syncthreads();
  if (threadIdx.x < 64) {
    const float v = acc[threadIdx.x][0] + acc[threadIdx.x][1] + acc[threadIdx.x][2] + acc[threadIdx.x][3];
    atomicAdd(&RS[threadIdx.x], v);
  }
}

// ---------------------------------------------------------------------------
// K3: global sum of w_pow for the write head (GS0).
// grid (16, 64): x = 4096-n superchunk, y = b. block 256.
// ---------------------------------------------------------------------------
__global__ __launch_bounds__(256) void gs0_kernel(
    const float* __restrict__ E0, const float* __restrict__ ww,
    const float* __restrict__ RS0, const float* __restrict__ g,
    const float* __restrict__ gamma_, const float* __restrict__ s,
    float* __restrict__ GS)
{
  const int b = blockIdx.y;
  const float gb = g[b], gmb = gamma_[b];
  const float s0 = s[b * 3], s1 = s[b * 3 + 1], s2 = s[b * 3 + 2];
  const float rinv = 1.0f / RS0[b];
  const float* Eb = E0 + (size_t)b * NN;
  const float* wb = ww + (size_t)b * NN;
  const int base = blockIdx.x * 4096;
  float acc = 0.f;
  for (int k = 0; k < 16; k++) {
    const int n = base + k * 256 + threadIdx.x;
    const float wgm = (n > 0) ? (gb * Eb[n - 1] * rinv + (1.f - gb) * wb[n - 1]) : 0.f;
    const float wgc = gb * Eb[n] * rinv + (1.f - gb) * wb[n];
    const float wgp = (n < NN - 1) ? (gb * Eb[n + 1] * rinv + (1.f - gb) * wb[n + 1]) : 0.f;
    const float wt = s0 * wgm + s1 * wgc + s2 * wgp;
    acc += fastPow(wt, gmb);
  }
  __shared__ float wsum[4];
  const float w = waveReduceSum(acc);
  if ((threadIdx.x & 63) == 0) wsum[threadIdx.x >> 6] = w;
  __syncthreads();
  if (threadIdx.x == 0) atomicAdd(&GS[0], wsum[0] + wsum[1] + wsum[2] + wsum[3]);
}

// ---------------------------------------------------------------------------
// K4: apply write head: m1 = m0*(1 - ww_new^T e) + ww_new^T a.
// grid 256, block 256 (thread per n). e/a fetched as wave-uniform loads,
// er/ad accumulators live in 128 VGPRs.
// ---------------------------------------------------------------------------
__global__ __launch_bounds__(256) void apply_write_kernel(
    const float* __restrict__ E0, const float* __restrict__ ww,
    const float* __restrict__ RS0, const float* __restrict__ g,
    const float* __restrict__ gamma_, const float* __restrict__ s,
    const float* __restrict__ GS,
    const float* __restrict__ e_v, const float* __restrict__ a_v,
    const float* __restrict__ memory, const int* __restrict__ bank,
    float* __restrict__ m1)
{
  const int n = blockIdx.x * 256 + threadIdx.x;
  const float* M0 = memory + (size_t)(*bank) * (size_t)NN * MM;
  const float invGS = 1.0f / (GS[0] + 1e-5f);
  float er[64], ad[64];
#pragma unroll
  for (int m = 0; m < 64; m++) { er[m] = 0.f; ad[m] = 0.f; }
  for (int b = 0; b < 64; b++) {
    const float gb = g[b], gmb = gamma_[b];
    const float s0 = s[b * 3], s1 = s[b * 3 + 1], s2 = s[b * 3 + 2];
    const float rinv = 1.0f / RS0[b];
    const float* Eb = E0 + (size_t)b * NN;
    const float* wb = ww + (size_t)b * NN;
    const float wgm = (n > 0) ? (gb * Eb[n - 1] * rinv + (1.f - gb) * wb[n - 1]) : 0.f;
    const float wgc = gb * Eb[n] * rinv + (1.f - gb) * wb[n];
    const float wgp = (n < NN - 1) ? (gb * Eb[n + 1] * rinv + (1.f - gb) * wb[n + 1]) : 0.f;
    const float wt = s0 * wgm + s1 * wgc + s2 * wgp;
    const float c = fastPow(wt, gmb) * invGS;
    const float4* e4 = (const float4*)(e_v + b * 64);
    const float4* a4 = (const float4*)(a_v + b * 64);
#pragma unroll
    for (int q = 0; q < 16; q++) {
      const float4 ev = e4[q], av = a4[q];
      er[q * 4 + 0] += c * ev.x; er[q * 4 + 1] += c * ev.y;
      er[q * 4 + 2] += c * ev.z; er[q * 4 + 3] += c * ev.w;
      ad[q * 4 + 0] += c * av.x; ad[q * 4 + 1] += c * av.y;
      ad[q * 4 + 2] += c * av.z; ad[q * 4 + 3] += c * av.w;
    }
  }
  const float4* m0p = (const float4*)(M0 + (size_t)n * MM);
  float4* m1p = (float4*)(m1 + (size_t)n * MM);
#pragma unroll
  for (int q = 0; q < 16; q++) {
    const float4 mv = m0p[q];
    float4 o;
    o.x = mv.x * (1.f - er[q * 4 + 0]) + ad[q * 4 + 0];
    o.y = mv.y * (1.f - er[q * 4 + 1]) + ad[q * 4 + 1];
    o.z = mv.z * (1.f - er[q * 4 + 2]) + ad[q * 4 + 2];
    o.w = mv.w * (1.f - er[q * 4 + 3]) + ad[q * 4 + 3];
    m1p[q] = o;
  }
}

// ---------------------------------------------------------------------------
// K6: read heads. For one r and 256-n superchunk: compute w_pow on the fly,
// stage (w_pow tile, m1 tile) in LDS (both row-pad 68 -> b128 reads), and
// accumulate out[b,m] partials in 4x4 register tiles. GS_r via atomics,
// output partials per superchunk (reduced in K7).
// grid (256, 4), block 256.
// ---------------------------------------------------------------------------
__global__ __launch_bounds__(256) void read_kernel(
    const float* __restrict__ E1, const float* __restrict__ wr,
    const float* __restrict__ RS1, const float* __restrict__ g,
    const float* __restrict__ gamma_, const float* __restrict__ sv,
    const float* __restrict__ m1,
    float* __restrict__ part, float* __restrict__ GS)
{
  const int r = blockIdx.y;
  const int sc = blockIdx.x;
  const int t = threadIdx.x;
  __shared__ float m1_sh[64 * 68];
  __shared__ float w_sh[64 * 68];
  __shared__ float wsum[4];
  float4 acc[4];
#pragma unroll
  for (int jb = 0; jb < 4; jb++) acc[jb] = make_float4(0.f, 0.f, 0.f, 0.f);
  float gs_acc = 0.f;
  const int lane = t & 63, wave = t >> 6;
  const int mq = t & 15, bq = t >> 4;
  const float* wrr = wr + (size_t)r * BB * NN;

  for (int tile = 0; tile < 4; tile++) {
    const int n0 = sc * 256 + tile * 64;
    __syncthreads();  // protect LDS from previous tile's readers
    // stage m1 tile [64n x 64m] -> m1_sh (pad 68)
#pragma unroll
    for (int rep = 0; rep < 4; rep++) {
      const int nl = rep * 16 + (t >> 4);
      const int mc = t & 15;
      const float4 v = ((const float4*)(m1 + (size_t)(n0 + nl) * MM))[mc];
      *((float4*)&m1_sh[nl * 68 + mc * 4]) = v;
    }
    // compute w_pow tile: lane = n_loc, wave covers 16 b's
    {
      const int n = n0 + lane;
      for (int i = 0; i < 16; i++) {
        const int b = wave * 16 + i;
        const float gb = g[b], gmb = gamma_[b];
        const float s0 = sv[b * 3], s1 = sv[b * 3 + 1], s2 = sv[b * 3 + 2];
        const float rinv = 1.0f / RS1[b];
        const float* Eb = E1 + (size_t)b * NN;
        const float* wb = wrr + (size_t)b * NN;
        const float wgm = (n > 0) ? (gb * Eb[n - 1] * rinv + (1.f - gb) * wb[n - 1]) : 0.f;
        const float wgc = gb * Eb[n] * rinv + (1.f - gb) * wb[n];
        const float wgp = (n < NN - 1) ? (gb * Eb[n + 1] * rinv + (1.f - gb) * wb[n + 1]) : 0.f;
        const float wt = s0 * wgm + s1 * wgc + s2 * wgp;
        const float wp = fastPow(wt, gmb);
        gs_acc += wp;
        w_sh[lane * 68 + b] = wp;
      }
    }
    __syncthreads();
    // accumulate: thread owns b = bq*4..+3 (via wv components), m = mq*4..+3
#pragma unroll 4
    for (int nn = 0; nn < 64; nn++) {
      const float4 mv = *((const float4*)&m1_sh[nn * 68 + mq * 4]);
      const float4 wv = *((const float4*)&w_sh[nn * 68 + bq * 4]);
      acc[0].x += wv.x * mv.x; acc[0].y += wv.x * mv.y; acc[0].z += wv.x * mv.z; acc[0].w += wv.x * mv.w;
      acc[1].x += wv.y * mv.x; acc[1].y += wv.y * mv.y; acc[1].z += wv.y * mv.z; acc[1].w += wv.y * mv.w;
      acc[2].x += wv.z * mv.x; acc[2].y += wv.z * mv.y; acc[2].z += wv.z * mv.z; acc[2].w += wv.z * mv.w;
      acc[3].x += wv.w * mv.x; acc[3].y += wv.w * mv.y; acc[3].z += wv.w * mv.z; acc[3].w += wv.w * mv.w;
    }
  }
  // write partials: part[sc][r][b][m]
  float* pp = part + ((size_t)(sc * 4 + r)) * 4096;
#pragma unroll
  for (int jb = 0; jb < 4; jb++) {
    *((float4*)&pp[(bq * 4 + jb) * 64 + mq * 4]) = acc[jb];
  }
  // GS_r
  const float w = waveReduceSum(gs_acc);
  if (lane == 0) wsum[wave] = w;
  __syncthreads();
  if (t == 0) atomicAdd(&GS[1 + r], wsum[0] + wsum[1] + wsum[2] + wsum[3]);
}

// ---------------------------------------------------------------------------
// K7: reduce superchunk partials and normalize by GS_r.
// grid 64, block 256. out[b][r*64+m].
// ---------------------------------------------------------------------------
__global__ __launch_bounds__(256) void finalize_kernel(
    const float* __restrict__ part, const float* __restrict__ GS,
    float* __restrict__ out)
{
  const int idx = blockIdx.x * 256 + threadIdx.x;  // 0..16383
  const int b = idx >> 8, rm = idx & 255, r = rm >> 6, m = rm & 63;
  const int off = r * 4096 + b * 64 + m;
  float sum = 0.f;
#pragma unroll 8
  for (int scq = 0; scq < 256; scq++) sum += part[scq * 16384 + off];
  out[idx] = sum / (GS[1 + r] + 1e-5f);
}

// ---------------------------------------------------------------------------
extern "C" void kernel_launch(void* const* d_in, const int* in_sizes, int n_in,
                              void* d_out, int out_size, void* d_ws, size_t ws_size,
                              hipStream_t stream) {
  (void)in_sizes; (void)n_in; (void)out_size; (void)ws_size;
  const float* h_t    = (const float*)d_in[0];
  const float* ww     = (const float*)d_in[1];
  const float* wr     = (const float*)d_in[2];
  const float* memory = (const float*)d_in[3];
  const float* key_w  = (const float*)d_in[4];
  const float* key_b  = (const float*)d_in[5];
  const float* beta_w = (const float*)d_in[6];
  const float* beta_b = (const float*)d_in[7];
  const float* gate_w = (const float*)d_in[8];
  const float* gate_b = (const float*)d_in[9];
  const float* shift_w = (const float*)d_in[10];
  const float* shift_b = (const float*)d_in[11];
  const float* gamma_w = (const float*)d_in[12];
  const float* gamma_b = (const float*)d_in[13];
  const float* erase_w = (const float*)d_in[14];
  const float* erase_b = (const float*)d_in[15];
  const float* add_w   = (const float*)d_in[16];
  const float* add_b   = (const float*)d_in[17];
  const int*   bank    = (const int*)d_in[18];

  float* ws = (float*)d_ws;
  float* E0   = ws;                  // 4,194,304 floats
  float* E1   = ws + 4194304;        // 4,194,304
  float* m1   = ws + 8388608;        // 4,194,304
  float* part = ws + 12582912;       // 4,194,304 (256 superchunks x 4 r x 64 b x 64 m)
  float* smallb = ws + 16777216;
  float* kn    = smallb;             // 4096
  float* e_v   = smallb + 4096;      // 4096
  float* a_v   = smallb + 8192;      // 4096
  float* beta  = smallb + 12288;     // 64
  float* g     = smallb + 12352;     // 64
  float* gam   = smallb + 12416;     // 64
  float* s     = smallb + 12480;     // 192
  float* RS0   = smallb + 12672;     // 64
  float* RS1   = smallb + 12736;     // 64
  float* GS    = smallb + 12800;     // 5: [0]=GS0, [1..4]=GS_r

  prep_kernel<<<64, 256, 0, stream>>>(h_t, key_w, key_b, beta_w, beta_b,
                                      gate_w, gate_b, shift_w, shift_b,
                                      gamma_w, gamma_b, erase_w, erase_b,
                                      add_w, add_b,
                                      kn, e_v, a_v, beta, g, gam, s, RS0, RS1, GS);
  content_kernel<<<256, 256, 0, stream>>>(memory, bank, kn, beta, E0, RS0);
  gs0_kernel<<<dim3(16, 64), 256, 0, stream>>>(E0, ww, RS0, g, gam, s, GS);
  apply_write_kernel<<<256, 256, 0, stream>>>(E0, ww, RS0, g, gam, s, GS,
                                              e_v, a_v, memory, bank, m1);
  content_kernel<<<256, 256, 0, stream>>>(m1, nullptr, kn, beta, E1, RS1);
  read_kernel<<<dim3(256, 4), 256, 0, stream>>>(E1, wr, RS1, g, gam, s, m1, part, GS);
  finalize_kernel<<<64, 256, 0, stream>>>(part, GS, (float*)d_out);
}

// Round 3
// 697.465 us; speedup vs baseline: 1.1469x; 1.1469x over previous
//
#include <hip/hip_runtime.h>

#define NN 65536
#define BB 64
#define HH 1024
#define MM 64
#define RR 4

__device__ __forceinline__ float waveReduceSum(float v) {
#pragma unroll
  for (int off = 32; off > 0; off >>= 1) v += __shfl_xor(v, off, 64);
  return v;
}

// fast pow for positive base: wt^p = exp(p * log(wt))
__device__ __forceinline__ float fastPow(float wt, float p) {
  return __expf(p * __logf(wt));
}

// ---------------------------------------------------------------------------
// K1: per-batch head parameters from h_t. grid 64, block 256.
// 4-way h-split partial dots for k/e/a (256-iter loops), then reduce in LDS.
// ---------------------------------------------------------------------------
__global__ __launch_bounds__(256) void prep_kernel(
    const float* __restrict__ h_t,
    const float* __restrict__ key_w, const float* __restrict__ key_b,
    const float* __restrict__ beta_w, const float* __restrict__ beta_b,
    const float* __restrict__ gate_w, const float* __restrict__ gate_b,
    const float* __restrict__ shift_w, const float* __restrict__ shift_b,
    const float* __restrict__ gamma_w, const float* __restrict__ gamma_b,
    const float* __restrict__ erase_w, const float* __restrict__ erase_b,
    const float* __restrict__ add_w, const float* __restrict__ add_b,
    float* __restrict__ kn, float* __restrict__ e_v, float* __restrict__ a_v,
    float* __restrict__ beta, float* __restrict__ g, float* __restrict__ gamma_,
    float* __restrict__ s,
    float* __restrict__ RS0, float* __restrict__ RS1, float* __restrict__ GS)
{
  const int b = blockIdx.x;
  const int t = threadIdx.x;
  __shared__ float h_sh[HH];
  __shared__ float part3[3][64][5];  // pad 5 to break 4-stride conflicts
  __shared__ float k_sh[64];
#pragma unroll
  for (int i = 0; i < 4; i++) h_sh[t + 256 * i] = h_t[b * HH + t + 256 * i];
  __syncthreads();

  const int c = t & 63, grp = t >> 6;
  const int h0 = grp * 256;
  float dk = 0.f, de = 0.f, da = 0.f;
#pragma unroll 4
  for (int i = 0; i < 256; i++) {
    const float hv = h_sh[h0 + i];
    dk += hv * key_w[(h0 + i) * 64 + c];
    de += hv * erase_w[(h0 + i) * 64 + c];
    da += hv * add_w[(h0 + i) * 64 + c];
  }
  part3[0][c][grp] = dk;
  part3[1][c][grp] = de;
  part3[2][c][grp] = da;
  __syncthreads();

  if (t < 64) {
    const float v = part3[0][t][0] + part3[0][t][1] + part3[0][t][2] + part3[0][t][3];
    k_sh[t] = fminf(fmaxf(v + key_b[t], 0.f), 1.f);
  } else if (t < 128) {
    const int m = t - 64;
    const float v = part3[1][m][0] + part3[1][m][1] + part3[1][m][2] + part3[1][m][3];
    e_v[b * 64 + m] = fminf(fmaxf(v + erase_b[m], 0.f), 1.f);
  } else if (t < 192) {
    const int m = t - 128;
    const float v = part3[2][m][0] + part3[2][m][1] + part3[2][m][2] + part3[2][m][3];
    a_v[b * 64 + m] = fminf(fmaxf(v + add_b[m], 0.f), 1.f);  // relu+clip01 == clip01
  } else {
    const int lane = t - 192;
    float outs[6];
#pragma unroll 1
    for (int o = 0; o < 6; o++) {
      float d = 0.f;
      if (o < 3) {
        const float* W = (o == 0) ? beta_w : ((o == 1) ? gate_w : gamma_w);
        for (int hh = lane; hh < HH; hh += 64) d += h_sh[hh] * W[hh];
      } else {
        const int j = o - 3;
        for (int hh = lane; hh < HH; hh += 64) d += h_sh[hh] * shift_w[hh * 3 + j];
      }
      outs[o] = waveReduceSum(d);
    }
    if (lane == 0) {
      beta[b]   = fmaxf(outs[0] + beta_b[0], 0.f);
      g[b]      = fminf(fmaxf(outs[1] + gate_b[0], 0.f), 1.f);
      gamma_[b] = 1.0f + fmaxf(outs[2] + gamma_b[0], 0.f);
      const float l0 = outs[3] + shift_b[0];
      const float l1 = outs[4] + shift_b[1];
      const float l2 = outs[5] + shift_b[2];
      const float mx = fmaxf(l0, fmaxf(l1, l2));
      const float e0 = __expf(l0 - mx), e1 = __expf(l1 - mx), e2 = __expf(l2 - mx);
      const float inv = 1.f / (e0 + e1 + e2);
      s[b * 3 + 0] = e0 * inv; s[b * 3 + 1] = e1 * inv; s[b * 3 + 2] = e2 * inv;
    }
  }
  __syncthreads();
  if (t < 64) {
    float ss = 0.f;
    for (int j = 0; j < 64; j++) ss += k_sh[j] * k_sh[j];
    kn[b * 64 + t] = k_sh[t] / (sqrtf(ss) + 1e-8f);
  }
  if (b == 0) {
    if (t < 64) { RS0[t] = 0.f; RS1[t] = 0.f; }
    if (t < 5) GS[t] = 0.f;
  }
}

// ---------------------------------------------------------------------------
// K2 / K5: content addressing. grid (256 n-chunks, 4 b-groups), block 256.
// thread-per-n, 16 b's per block. E[b,n] = exp(beta*cos), RS[b] += row sums.
// ---------------------------------------------------------------------------
__global__ __launch_bounds__(256, 4) void content_kernel(
    const float* __restrict__ mem, const int* __restrict__ bank,
    const float* __restrict__ kn, const float* __restrict__ beta,
    float* __restrict__ E, float* __restrict__ RS)
{
  const float* Mrow = mem + (bank ? ((size_t)(*bank) * (size_t)NN * MM) : (size_t)0);
  const int n = blockIdx.x * 256 + threadIdx.x;
  const int b0 = blockIdx.y * 16;
  float4 row[16];
  const float4* rp = (const float4*)(Mrow + (size_t)n * MM);
#pragma unroll
  for (int q = 0; q < 16; q++) row[q] = rp[q];
  float ss = 0.f;
#pragma unroll
  for (int q = 0; q < 16; q++)
    ss += row[q].x * row[q].x + row[q].y * row[q].y + row[q].z * row[q].z + row[q].w * row[q].w;
  const float rinv = 1.0f / (sqrtf(ss) + 1e-8f);

  __shared__ float acc[16][4];
  const int wid = threadIdx.x >> 6;
  const int lane = threadIdx.x & 63;
  for (int i = 0; i < 16; i++) {
    const int b = b0 + i;
    const float4* kp = (const float4*)(kn + b * 64);
    float dot = 0.f;
#pragma unroll
    for (int q = 0; q < 16; q++) {
      const float4 kq = kp[q];
      dot += kq.x * row[q].x + kq.y * row[q].y + kq.z * row[q].z + kq.w * row[q].w;
    }
    const float e = __expf(beta[b] * dot * rinv);
    E[(size_t)b * NN + n] = e;
    const float r = waveReduceSum(e);
    if (lane == 0) acc[i][wid] = r;
  }
  __syncthreads();
  if (threadIdx.x < 16) {
    const float v = acc[threadIdx.x][0] + acc[threadIdx.x][1] + acc[threadIdx.x][2] + acc[threadIdx.x][3];
    atomicAdd(&RS[b0 + threadIdx.x], v);
  }
}

// ---------------------------------------------------------------------------
// K3: global sum of w_pow for the write head (GS0). grid (32, 64), block 256.
// ---------------------------------------------------------------------------
__global__ __launch_bounds__(256, 4) void gs0_kernel(
    const float* __restrict__ E0, const float* __restrict__ ww,
    const float* __restrict__ RS0, const float* __restrict__ g,
    const float* __restrict__ gamma_, const float* __restrict__ s,
    float* __restrict__ GS)
{
  const int b = blockIdx.y;
  const float gb = g[b], gmb = gamma_[b];
  const float s0 = s[b * 3], s1 = s[b * 3 + 1], s2 = s[b * 3 + 2];
  const float rinv = 1.0f / RS0[b];
  const float* Eb = E0 + (size_t)b * NN;
  const float* wb = ww + (size_t)b * NN;
  const int base = blockIdx.x * 2048;
  float acc = 0.f;
  for (int k = 0; k < 8; k++) {
    const int n = base + k * 256 + threadIdx.x;
    const float wgm = (n > 0) ? (gb * Eb[n - 1] * rinv + (1.f - gb) * wb[n - 1]) : 0.f;
    const float wgc = gb * Eb[n] * rinv + (1.f - gb) * wb[n];
    const float wgp = (n < NN - 1) ? (gb * Eb[n + 1] * rinv + (1.f - gb) * wb[n + 1]) : 0.f;
    const float wt = s0 * wgm + s1 * wgc + s2 * wgp;
    acc += fastPow(wt, gmb);
  }
  __shared__ float wsum[4];
  const float w = waveReduceSum(acc);
  if ((threadIdx.x & 63) == 0) wsum[threadIdx.x >> 6] = w;
  __syncthreads();
  if (threadIdx.x == 0) atomicAdd(&GS[0], wsum[0] + wsum[1] + wsum[2] + wsum[3]);
}

// ---------------------------------------------------------------------------
// K4: apply write head. grid 1024 (64-n blocks), block 256.
// Phase 1: cw[b][nl] = w_pow * invGS into LDS (conflict-free [b][66]).
// Phase 2: thread = (nl = t>>2, mq = t&3): er/ad[16] rank-64 update, e/a in LDS.
// ---------------------------------------------------------------------------
__global__ __launch_bounds__(256, 4) void apply_write_kernel(
    const float* __restrict__ E0, const float* __restrict__ ww,
    const float* __restrict__ RS0, const float* __restrict__ g,
    const float* __restrict__ gamma_, const float* __restrict__ s,
    const float* __restrict__ GS,
    const float* __restrict__ e_v, const float* __restrict__ a_v,
    const float* __restrict__ memory, const int* __restrict__ bank,
    float* __restrict__ m1)
{
  __shared__ float cw[64 * 66];
  __shared__ float e_sh[4096];
  __shared__ float a_sh[4096];
  const int t = threadIdx.x;
  // stage e/a (4096 floats each)
#pragma unroll
  for (int q = 0; q < 4; q++) {
    ((float4*)e_sh)[t + 256 * q] = ((const float4*)e_v)[t + 256 * q];
    ((float4*)a_sh)[t + 256 * q] = ((const float4*)a_v)[t + 256 * q];
  }
  const int n0 = blockIdx.x * 64;
  const int lane = t & 63, wave = t >> 6;
  const float invGS = 1.0f / (GS[0] + 1e-5f);
  // phase 1: w_pow tile
  {
    const int n = n0 + lane;
    for (int i = 0; i < 16; i++) {
      const int b = wave * 16 + i;
      const float gb = g[b], gmb = gamma_[b];
      const float s0 = s[b * 3], s1 = s[b * 3 + 1], s2 = s[b * 3 + 2];
      const float rinv = 1.0f / RS0[b];
      const float* Eb = E0 + (size_t)b * NN;
      const float* wb = ww + (size_t)b * NN;
      const float wgm = (n > 0) ? (gb * Eb[n - 1] * rinv + (1.f - gb) * wb[n - 1]) : 0.f;
      const float wgc = gb * Eb[n] * rinv + (1.f - gb) * wb[n];
      const float wgp = (n < NN - 1) ? (gb * Eb[n + 1] * rinv + (1.f - gb) * wb[n + 1]) : 0.f;
      const float wt = s0 * wgm + s1 * wgc + s2 * wgp;
      cw[b * 66 + lane] = fastPow(wt, gmb) * invGS;
    }
  }
  __syncthreads();
  // phase 2
  const int nl = t >> 2, mq = t & 3;
  const int n = n0 + nl;
  float er[16], ad[16];
#pragma unroll
  for (int j = 0; j < 16; j++) { er[j] = 0.f; ad[j] = 0.f; }
  for (int b = 0; b < 64; b++) {
    const float c = cw[b * 66 + nl];
#pragma unroll
    for (int j = 0; j < 4; j++) {
      const float4 ev = *((const float4*)&e_sh[b * 64 + mq * 16 + j * 4]);
      const float4 av = *((const float4*)&a_sh[b * 64 + mq * 16 + j * 4]);
      er[j * 4 + 0] += c * ev.x; er[j * 4 + 1] += c * ev.y;
      er[j * 4 + 2] += c * ev.z; er[j * 4 + 3] += c * ev.w;
      ad[j * 4 + 0] += c * av.x; ad[j * 4 + 1] += c * av.y;
      ad[j * 4 + 2] += c * av.z; ad[j * 4 + 3] += c * av.w;
    }
  }
  const float* M0 = memory + (size_t)(*bank) * (size_t)NN * MM;
  const float4* m0p = (const float4*)(M0 + (size_t)n * MM + mq * 16);
  float4* m1p = (float4*)(m1 + (size_t)n * MM + mq * 16);
#pragma unroll
  for (int j = 0; j < 4; j++) {
    const float4 mv = m0p[j];
    float4 o;
    o.x = mv.x * (1.f - er[j * 4 + 0]) + ad[j * 4 + 0];
    o.y = mv.y * (1.f - er[j * 4 + 1]) + ad[j * 4 + 1];
    o.z = mv.z * (1.f - er[j * 4 + 2]) + ad[j * 4 + 2];
    o.w = mv.w * (1.f - er[j * 4 + 3]) + ad[j * 4 + 3];
    m1p[j] = o;
  }
}

// ---------------------------------------------------------------------------
// K6: read heads. grid (256, 4), block 256, __launch_bounds__(256,4) so all
// 4 blocks/CU (16 waves) stay resident. w tile LDS layout [b][66]:
// conflict-free writes, broadcast scalar reads.
// ---------------------------------------------------------------------------
__global__ __launch_bounds__(256, 4) void read_kernel(
    const float* __restrict__ E1, const float* __restrict__ wr,
    const float* __restrict__ RS1, const float* __restrict__ g,
    const float* __restrict__ gamma_, const float* __restrict__ sv,
    const float* __restrict__ m1,
    float* __restrict__ part, float* __restrict__ GS)
{
  const int r = blockIdx.y;
  const int sc = blockIdx.x;
  const int t = threadIdx.x;
  __shared__ float m1_sh[64 * 68];
  __shared__ float w_sh[64 * 66];
  __shared__ float wsum[4];
  float4 acc[4];
#pragma unroll
  for (int jb = 0; jb < 4; jb++) acc[jb] = make_float4(0.f, 0.f, 0.f, 0.f);
  float gs_acc = 0.f;
  const int lane = t & 63, wave = t >> 6;
  const int mq = t & 15, bq = t >> 4;
  const float* wrr = wr + (size_t)r * BB * NN;

  for (int tile = 0; tile < 4; tile++) {
    const int n0 = sc * 256 + tile * 64;
    __syncthreads();
    // stage m1 tile [64n x 64m] -> m1_sh (pad 68)
#pragma unroll
    for (int rep = 0; rep < 4; rep++) {
      const int nl = rep * 16 + (t >> 4);
      const int mc = t & 15;
      const float4 v = ((const float4*)(m1 + (size_t)(n0 + nl) * MM))[mc];
      *((float4*)&m1_sh[nl * 68 + mc * 4]) = v;
    }
    // compute w_pow tile into w_sh[b][66]
    {
      const int n = n0 + lane;
      for (int i = 0; i < 16; i++) {
        const int b = wave * 16 + i;
        const float gb = g[b], gmb = gamma_[b];
        const float s0 = sv[b * 3], s1 = sv[b * 3 + 1], s2 = sv[b * 3 + 2];
        const float rinv = 1.0f / RS1[b];
        const float* Eb = E1 + (size_t)b * NN;
        const float* wb = wrr + (size_t)b * NN;
        const float wgm = (n > 0) ? (gb * Eb[n - 1] * rinv + (1.f - gb) * wb[n - 1]) : 0.f;
        const float wgc = gb * Eb[n] * rinv + (1.f - gb) * wb[n];
        const float wgp = (n < NN - 1) ? (gb * Eb[n + 1] * rinv + (1.f - gb) * wb[n + 1]) : 0.f;
        const float wt = s0 * wgm + s1 * wgc + s2 * wgp;
        const float wp = fastPow(wt, gmb);
        gs_acc += wp;
        w_sh[b * 66 + lane] = wp;
      }
    }
    __syncthreads();
    // accumulate: thread owns b = bq*4..+3, m = mq*4..+3
#pragma unroll 4
    for (int nn = 0; nn < 64; nn++) {
      const float4 mv = *((const float4*)&m1_sh[nn * 68 + mq * 4]);
      const float w0 = w_sh[(bq * 4 + 0) * 66 + nn];
      const float w1 = w_sh[(bq * 4 + 1) * 66 + nn];
      const float w2 = w_sh[(bq * 4 + 2) * 66 + nn];
      const float w3 = w_sh[(bq * 4 + 3) * 66 + nn];
      acc[0].x += w0 * mv.x; acc[0].y += w0 * mv.y; acc[0].z += w0 * mv.z; acc[0].w += w0 * mv.w;
      acc[1].x += w1 * mv.x; acc[1].y += w1 * mv.y; acc[1].z += w1 * mv.z; acc[1].w += w1 * mv.w;
      acc[2].x += w2 * mv.x; acc[2].y += w2 * mv.y; acc[2].z += w2 * mv.z; acc[2].w += w2 * mv.w;
      acc[3].x += w3 * mv.x; acc[3].y += w3 * mv.y; acc[3].z += w3 * mv.z; acc[3].w += w3 * mv.w;
    }
  }
  // write partials: part[sc][r][b][m]
  float* pp = part + ((size_t)(sc * 4 + r)) * 4096;
#pragma unroll
  for (int jb = 0; jb < 4; jb++) {
    *((float4*)&pp[(bq * 4 + jb) * 64 + mq * 4]) = acc[jb];
  }
  // GS_r
  const float w = waveReduceSum(gs_acc);
  if (lane == 0) wsum[wave] = w;
  __syncthreads();
  if (t == 0) atomicAdd(&GS[1 + r], wsum[0] + wsum[1] + wsum[2] + wsum[3]);
}

// ---------------------------------------------------------------------------
// K7: reduce superchunk partials and normalize by GS_r. grid 64, block 256.
// ---------------------------------------------------------------------------
__global__ __launch_bounds__(256) void finalize_kernel(
    const float* __restrict__ part, const float* __restrict__ GS,
    float* __restrict__ out)
{
  const int idx = blockIdx.x * 256 + threadIdx.x;  // 0..16383
  const int b = idx >> 8, rm = idx & 255, r = rm >> 6, m = rm & 63;
  const int off = r * 4096 + b * 64 + m;
  float sum = 0.f;
#pragma unroll 8
  for (int scq = 0; scq < 256; scq++) sum += part[scq * 16384 + off];
  out[idx] = sum / (GS[1 + r] + 1e-5f);
}

// ---------------------------------------------------------------------------
extern "C" void kernel_launch(void* const* d_in, const int* in_sizes, int n_in,
                              void* d_out, int out_size, void* d_ws, size_t ws_size,
                              hipStream_t stream) {
  (void)in_sizes; (void)n_in; (void)out_size; (void)ws_size;
  const float* h_t    = (const float*)d_in[0];
  const float* ww     = (const float*)d_in[1];
  const float* wr     = (const float*)d_in[2];
  const float* memory = (const float*)d_in[3];
  const float* key_w  = (const float*)d_in[4];
  const float* key_b  = (const float*)d_in[5];
  const float* beta_w = (const float*)d_in[6];
  const float* beta_b = (const float*)d_in[7];
  const float* gate_w = (const float*)d_in[8];
  const float* gate_b = (const float*)d_in[9];
  const float* shift_w = (const float*)d_in[10];
  const float* shift_b = (const float*)d_in[11];
  const float* gamma_w = (const float*)d_in[12];
  const float* gamma_b = (const float*)d_in[13];
  const float* erase_w = (const float*)d_in[14];
  const float* erase_b = (const float*)d_in[15];
  const float* add_w   = (const float*)d_in[16];
  const float* add_b   = (const float*)d_in[17];
  const int*   bank    = (const int*)d_in[18];

  float* ws = (float*)d_ws;
  float* E0   = ws;                  // 4,194,304 floats
  float* E1   = ws + 4194304;        // 4,194,304
  float* m1   = ws + 8388608;        // 4,194,304
  float* part = ws + 12582912;       // 4,194,304 (256 sc x 4 r x 64 b x 64 m)
  float* smallb = ws + 16777216;
  float* kn    = smallb;             // 4096
  float* e_v   = smallb + 4096;      // 4096
  float* a_v   = smallb + 8192;      // 4096
  float* beta  = smallb + 12288;     // 64
  float* g     = smallb + 12352;     // 64
  float* gam   = smallb + 12416;     // 64
  float* s     = smallb + 12480;     // 192
  float* RS0   = smallb + 12672;     // 64
  float* RS1   = smallb + 12736;     // 64
  float* GS    = smallb + 12800;     // 5: [0]=GS0, [1..4]=GS_r

  prep_kernel<<<64, 256, 0, stream>>>(h_t, key_w, key_b, beta_w, beta_b,
                                      gate_w, gate_b, shift_w, shift_b,
                                      gamma_w, gamma_b, erase_w, erase_b,
                                      add_w, add_b,
                                      kn, e_v, a_v, beta, g, gam, s, RS0, RS1, GS);
  content_kernel<<<dim3(256, 4), 256, 0, stream>>>(memory, bank, kn, beta, E0, RS0);
  gs0_kernel<<<dim3(32, 64), 256, 0, stream>>>(E0, ww, RS0, g, gam, s, GS);
  apply_write_kernel<<<1024, 256, 0, stream>>>(E0, ww, RS0, g, gam, s, GS,
                                               e_v, a_v, memory, bank, m1);
  content_kernel<<<dim3(256, 4), 256, 0, stream>>>(m1, nullptr, kn, beta, E1, RS1);
  read_kernel<<<dim3(256, 4), 256, 0, stream>>>(E1, wr, RS1, g, gam, s, m1, part, GS);
  finalize_kernel<<<64, 256, 0, stream>>>(part, GS, (float*)d_out);
}

// Round 4
// 655.081 us; speedup vs baseline: 1.2211x; 1.0647x over previous
//
#include <hip/hip_runtime.h>

#define NN 65536
#define BB 64
#define HH 1024
#define MM 64
#define RR 4

__device__ __forceinline__ float waveReduceSum(float v) {
#pragma unroll
  for (int off = 32; off > 0; off >>= 1) v += __shfl_xor(v, off, 64);
  return v;
}

// fast pow for positive base: wt^p = exp(p * log(wt))
__device__ __forceinline__ float fastPow(float wt, float p) {
  return __expf(p * __logf(wt));
}

// shifted, gated interpolation weight at n (lane == n % 64).
// wg(x) = gb*E[x]*rinv + (1-gb)*w[x]; returns s0*wg(n-1)+s1*wg(n)+s2*wg(n+1)
// Neighbors come from adjacent lanes via shfl; lanes 0/63 reload the halo.
__device__ __forceinline__ float shifted_wg(
    const float* __restrict__ Eb, const float* __restrict__ wb, int n,
    float gb, float rinv, float s0, float s1, float s2) {
  const int lane = threadIdx.x & 63;
  const float omg = 1.f - gb;
  const float wgc = gb * Eb[n] * rinv + omg * wb[n];
  float wgm = __shfl_up(wgc, 1, 64);
  float wgp = __shfl_down(wgc, 1, 64);
  if (lane == 0)  wgm = (n > 0)      ? (gb * Eb[n - 1] * rinv + omg * wb[n - 1]) : 0.f;
  if (lane == 63) wgp = (n < NN - 1) ? (gb * Eb[n + 1] * rinv + omg * wb[n + 1]) : 0.f;
  return s0 * wgm + s1 * wgc + s2 * wgp;
}

// ---------------------------------------------------------------------------
// K1: per-batch head parameters from h_t. grid 64, block 256.
// ---------------------------------------------------------------------------
__global__ __launch_bounds__(256) void prep_kernel(
    const float* __restrict__ h_t,
    const float* __restrict__ key_w, const float* __restrict__ key_b,
    const float* __restrict__ beta_w, const float* __restrict__ beta_b,
    const float* __restrict__ gate_w, const float* __restrict__ gate_b,
    const float* __restrict__ shift_w, const float* __restrict__ shift_b,
    const float* __restrict__ gamma_w, const float* __restrict__ gamma_b,
    const float* __restrict__ erase_w, const float* __restrict__ erase_b,
    const float* __restrict__ add_w, const float* __restrict__ add_b,
    float* __restrict__ kn, float* __restrict__ e_v, float* __restrict__ a_v,
    float* __restrict__ beta, float* __restrict__ g, float* __restrict__ gamma_,
    float* __restrict__ s,
    float* __restrict__ RS0, float* __restrict__ RS1, float* __restrict__ GS)
{
  const int b = blockIdx.x;
  const int t = threadIdx.x;
  __shared__ float h_sh[HH];
  __shared__ float part3[3][64][5];
  __shared__ float k_sh[64];
#pragma unroll
  for (int i = 0; i < 4; i++) h_sh[t + 256 * i] = h_t[b * HH + t + 256 * i];
  __syncthreads();

  const int c = t & 63, grp = t >> 6;
  const int h0 = grp * 256;
  float dk = 0.f, de = 0.f, da = 0.f;
#pragma unroll 4
  for (int i = 0; i < 256; i++) {
    const float hv = h_sh[h0 + i];
    dk += hv * key_w[(h0 + i) * 64 + c];
    de += hv * erase_w[(h0 + i) * 64 + c];
    da += hv * add_w[(h0 + i) * 64 + c];
  }
  part3[0][c][grp] = dk;
  part3[1][c][grp] = de;
  part3[2][c][grp] = da;
  __syncthreads();

  if (t < 64) {
    const float v = part3[0][t][0] + part3[0][t][1] + part3[0][t][2] + part3[0][t][3];
    k_sh[t] = fminf(fmaxf(v + key_b[t], 0.f), 1.f);
  } else if (t < 128) {
    const int m = t - 64;
    const float v = part3[1][m][0] + part3[1][m][1] + part3[1][m][2] + part3[1][m][3];
    e_v[b * 64 + m] = fminf(fmaxf(v + erase_b[m], 0.f), 1.f);
  } else if (t < 192) {
    const int m = t - 128;
    const float v = part3[2][m][0] + part3[2][m][1] + part3[2][m][2] + part3[2][m][3];
    a_v[b * 64 + m] = fminf(fmaxf(v + add_b[m], 0.f), 1.f);  // relu+clip01 == clip01
  } else {
    const int lane = t - 192;
    float outs[6];
#pragma unroll 1
    for (int o = 0; o < 6; o++) {
      float d = 0.f;
      if (o < 3) {
        const float* W = (o == 0) ? beta_w : ((o == 1) ? gate_w : gamma_w);
        for (int hh = lane; hh < HH; hh += 64) d += h_sh[hh] * W[hh];
      } else {
        const int j = o - 3;
        for (int hh = lane; hh < HH; hh += 64) d += h_sh[hh] * shift_w[hh * 3 + j];
      }
      outs[o] = waveReduceSum(d);
    }
    if (lane == 0) {
      beta[b]   = fmaxf(outs[0] + beta_b[0], 0.f);
      g[b]      = fminf(fmaxf(outs[1] + gate_b[0], 0.f), 1.f);
      gamma_[b] = 1.0f + fmaxf(outs[2] + gamma_b[0], 0.f);
      const float l0 = outs[3] + shift_b[0];
      const float l1 = outs[4] + shift_b[1];
      const float l2 = outs[5] + shift_b[2];
      const float mx = fmaxf(l0, fmaxf(l1, l2));
      const float e0 = __expf(l0 - mx), e1 = __expf(l1 - mx), e2 = __expf(l2 - mx);
      const float inv = 1.f / (e0 + e1 + e2);
      s[b * 3 + 0] = e0 * inv; s[b * 3 + 1] = e1 * inv; s[b * 3 + 2] = e2 * inv;
    }
  }
  __syncthreads();
  if (t < 64) {
    float ss = 0.f;
    for (int j = 0; j < 64; j++) ss += k_sh[j] * k_sh[j];
    kn[b * 64 + t] = k_sh[t] / (sqrtf(ss) + 1e-8f);
  }
  if (b == 0) {
    if (t < 64) { RS0[t] = 0.f; RS1[t] = 0.f; }
    if (t < 5) GS[t] = 0.f;
  }
}

// ---------------------------------------------------------------------------
// K2 / K5: content addressing. grid 512 (128-n per block), block 256.
// Each block handles all 64 b: memory rows fetched exactly once.
// thread: nl = t&127, half = t>>7 -> b in [half*32, half*32+32).
// ---------------------------------------------------------------------------
__global__ void content_kernel(
    const float* __restrict__ mem, const int* __restrict__ bank,
    const float* __restrict__ kn, const float* __restrict__ beta,
    float* __restrict__ E, float* __restrict__ RS)
{
  const float* Mrow = mem + (bank ? ((size_t)(*bank) * (size_t)NN * MM) : (size_t)0);
  const int t = threadIdx.x;
  const int nl = t & 127, half = t >> 7;
  const int n = blockIdx.x * 128 + nl;
  const int lane = t & 63, wave = t >> 6;

  __shared__ float k_sh[4096];
  __shared__ float b_sh[64];
  __shared__ float accs[64][2];
#pragma unroll
  for (int q = 0; q < 4; q++)
    ((float4*)k_sh)[t + 256 * q] = ((const float4*)kn)[t + 256 * q];
  if (t < 64) b_sh[t] = beta[t];

  float4 row[16];
  const float4* rp = (const float4*)(Mrow + (size_t)n * MM);
#pragma unroll
  for (int q = 0; q < 16; q++) row[q] = rp[q];
  float ss = 0.f;
#pragma unroll
  for (int q = 0; q < 16; q++)
    ss += row[q].x * row[q].x + row[q].y * row[q].y + row[q].z * row[q].z + row[q].w * row[q].w;
  const float rinv = 1.0f / (sqrtf(ss) + 1e-8f);
  __syncthreads();

  for (int i = 0; i < 32; i++) {
    const int b = half * 32 + i;
    const float4* kp = (const float4*)&k_sh[b * 64];
    float dot = 0.f;
#pragma unroll
    for (int q = 0; q < 16; q++) {
      const float4 kq = kp[q];
      dot += kq.x * row[q].x + kq.y * row[q].y + kq.z * row[q].z + kq.w * row[q].w;
    }
    const float e = __expf(b_sh[b] * dot * rinv);
    E[(size_t)b * NN + n] = e;
    const float r = waveReduceSum(e);
    if (lane == 0) accs[b][wave & 1] = r;
  }
  __syncthreads();
  if (t < 64) atomicAdd(&RS[t], accs[t][0] + accs[t][1]);
}

// ---------------------------------------------------------------------------
// K3: global sum of w_pow for the write head (GS0). grid (32, 64), block 256.
// ---------------------------------------------------------------------------
__global__ __launch_bounds__(256, 2) void gs0_kernel(
    const float* __restrict__ E0, const float* __restrict__ ww,
    const float* __restrict__ RS0, const float* __restrict__ g,
    const float* __restrict__ gamma_, const float* __restrict__ s,
    float* __restrict__ GS)
{
  const int b = blockIdx.y;
  const float gb = g[b], gmb = gamma_[b];
  const float s0 = s[b * 3], s1 = s[b * 3 + 1], s2 = s[b * 3 + 2];
  const float rinv = 1.0f / RS0[b];
  const float* Eb = E0 + (size_t)b * NN;
  const float* wb = ww + (size_t)b * NN;
  const int base = blockIdx.x * 2048;
  float acc = 0.f;
  for (int k = 0; k < 8; k++) {
    const int n = base + k * 256 + threadIdx.x;
    const float wt = shifted_wg(Eb, wb, n, gb, rinv, s0, s1, s2);
    acc += fastPow(wt, gmb);
  }
  __shared__ float wsum[4];
  const float w = waveReduceSum(acc);
  if ((threadIdx.x & 63) == 0) wsum[threadIdx.x >> 6] = w;
  __syncthreads();
  if (threadIdx.x == 0) atomicAdd(&GS[0], wsum[0] + wsum[1] + wsum[2] + wsum[3]);
}

// ---------------------------------------------------------------------------
// K4: apply write head. grid 1024 (64-n blocks), block 256.
// Phase 1: cw[b][nl] = w_pow * invGS into LDS (shfl shift trick).
// Phase 2: thread = (nl = t>>2, mq = t&3): er/ad[16] rank-64 update, e/a in LDS.
// ---------------------------------------------------------------------------
__global__ __launch_bounds__(256, 3) void apply_write_kernel(
    const float* __restrict__ E0, const float* __restrict__ ww,
    const float* __restrict__ RS0, const float* __restrict__ g,
    const float* __restrict__ gamma_, const float* __restrict__ s,
    const float* __restrict__ GS,
    const float* __restrict__ e_v, const float* __restrict__ a_v,
    const float* __restrict__ memory, const int* __restrict__ bank,
    float* __restrict__ m1)
{
  __shared__ float cw[64 * 66];
  __shared__ float e_sh[4096];
  __shared__ float a_sh[4096];
  const int t = threadIdx.x;
#pragma unroll
  for (int q = 0; q < 4; q++) {
    ((float4*)e_sh)[t + 256 * q] = ((const float4*)e_v)[t + 256 * q];
    ((float4*)a_sh)[t + 256 * q] = ((const float4*)a_v)[t + 256 * q];
  }
  const int n0 = blockIdx.x * 64;
  const int lane = t & 63, wave = t >> 6;
  const float invGS = 1.0f / (GS[0] + 1e-5f);
  // phase 1: w_pow tile
  {
    const int n = n0 + lane;
#pragma unroll 4
    for (int i = 0; i < 16; i++) {
      const int b = wave * 16 + i;
      const float gb = g[b], gmb = gamma_[b];
      const float s0 = s[b * 3], s1 = s[b * 3 + 1], s2 = s[b * 3 + 2];
      const float rinv = 1.0f / RS0[b];
      const float wt = shifted_wg(E0 + (size_t)b * NN, ww + (size_t)b * NN, n,
                                  gb, rinv, s0, s1, s2);
      cw[b * 66 + lane] = fastPow(wt, gmb) * invGS;
    }
  }
  __syncthreads();
  // phase 2
  const int nl = t >> 2, mq = t & 3;
  const int n = n0 + nl;
  float er[16], ad[16];
#pragma unroll
  for (int j = 0; j < 16; j++) { er[j] = 0.f; ad[j] = 0.f; }
  for (int b = 0; b < 64; b++) {
    const float c = cw[b * 66 + nl];
#pragma unroll
    for (int j = 0; j < 4; j++) {
      const float4 ev = *((const float4*)&e_sh[b * 64 + mq * 16 + j * 4]);
      const float4 av = *((const float4*)&a_sh[b * 64 + mq * 16 + j * 4]);
      er[j * 4 + 0] += c * ev.x; er[j * 4 + 1] += c * ev.y;
      er[j * 4 + 2] += c * ev.z; er[j * 4 + 3] += c * ev.w;
      ad[j * 4 + 0] += c * av.x; ad[j * 4 + 1] += c * av.y;
      ad[j * 4 + 2] += c * av.z; ad[j * 4 + 3] += c * av.w;
    }
  }
  const float* M0 = memory + (size_t)(*bank) * (size_t)NN * MM;
  const float4* m0p = (const float4*)(M0 + (size_t)n * MM + mq * 16);
  float4* m1p = (float4*)(m1 + (size_t)n * MM + mq * 16);
#pragma unroll
  for (int j = 0; j < 4; j++) {
    const float4 mv = m0p[j];
    float4 o;
    o.x = mv.x * (1.f - er[j * 4 + 0]) + ad[j * 4 + 0];
    o.y = mv.y * (1.f - er[j * 4 + 1]) + ad[j * 4 + 1];
    o.z = mv.z * (1.f - er[j * 4 + 2]) + ad[j * 4 + 2];
    o.w = mv.w * (1.f - er[j * 4 + 3]) + ad[j * 4 + 3];
    m1p[j] = o;
  }
}

// ---------------------------------------------------------------------------
// K6: read heads. grid 512 (128-n per block), block 256; ALL 4 r per block
// (E1/m1 fetched once). Per 64-n tile: stage m1, then per r compute w_pow
// tile (shfl shift) -> w_sh, accumulate 4x4 register tiles into acc[r].
// ---------------------------------------------------------------------------
__global__ __launch_bounds__(256, 2) void read_kernel(
    const float* __restrict__ E1, const float* __restrict__ wr,
    const float* __restrict__ RS1, const float* __restrict__ g,
    const float* __restrict__ gamma_, const float* __restrict__ sv,
    const float* __restrict__ m1,
    float* __restrict__ part, float* __restrict__ GS)
{
  const int sc = blockIdx.x;  // 128-n superchunk
  const int t = threadIdx.x;
  __shared__ float m1_sh[64 * 68];
  __shared__ float w_sh[64 * 66];
  __shared__ float wsum[4][4];
  float4 acc[4][4];
#pragma unroll
  for (int r = 0; r < 4; r++)
#pragma unroll
    for (int jb = 0; jb < 4; jb++) acc[r][jb] = make_float4(0.f, 0.f, 0.f, 0.f);
  float gs_acc[4] = {0.f, 0.f, 0.f, 0.f};
  const int lane = t & 63, wave = t >> 6;
  const int mq = t & 15, bq = t >> 4;

  for (int tile = 0; tile < 2; tile++) {
    const int n0 = sc * 128 + tile * 64;
    __syncthreads();  // protect m1_sh/w_sh from previous tile's readers
    // stage m1 tile [64n x 64m] -> m1_sh (pad 68)
#pragma unroll
    for (int rep = 0; rep < 4; rep++) {
      const int nl = rep * 16 + (t >> 4);
      const int mc = t & 15;
      const float4 v = ((const float4*)(m1 + (size_t)(n0 + nl) * MM))[mc];
      *((float4*)&m1_sh[nl * 68 + mc * 4]) = v;
    }
    for (int r = 0; r < 4; r++) {
      if (r > 0) __syncthreads();  // done reading previous r's w_sh
      // compute w_pow tile into w_sh[b][66]
      {
        const int n = n0 + lane;
        const float* wrr = wr + (size_t)r * BB * NN;
#pragma unroll 4
        for (int i = 0; i < 16; i++) {
          const int b = wave * 16 + i;
          const float gb = g[b], gmb = gamma_[b];
          const float s0 = sv[b * 3], s1 = sv[b * 3 + 1], s2 = sv[b * 3 + 2];
          const float rinv = 1.0f / RS1[b];
          const float wt = shifted_wg(E1 + (size_t)b * NN, wrr + (size_t)b * NN,
                                      n, gb, rinv, s0, s1, s2);
          const float wp = fastPow(wt, gmb);
          gs_acc[r] += wp;
          w_sh[b * 66 + lane] = wp;
        }
      }
      __syncthreads();
      // accumulate: thread owns b = bq*4..+3, m = mq*4..+3
#pragma unroll 4
      for (int nn = 0; nn < 64; nn++) {
        const float4 mv = *((const float4*)&m1_sh[nn * 68 + mq * 4]);
        const float w0 = w_sh[(bq * 4 + 0) * 66 + nn];
        const float w1 = w_sh[(bq * 4 + 1) * 66 + nn];
        const float w2 = w_sh[(bq * 4 + 2) * 66 + nn];
        const float w3 = w_sh[(bq * 4 + 3) * 66 + nn];
        acc[r][0].x += w0 * mv.x; acc[r][0].y += w0 * mv.y; acc[r][0].z += w0 * mv.z; acc[r][0].w += w0 * mv.w;
        acc[r][1].x += w1 * mv.x; acc[r][1].y += w1 * mv.y; acc[r][1].z += w1 * mv.z; acc[r][1].w += w1 * mv.w;
        acc[r][2].x += w2 * mv.x; acc[r][2].y += w2 * mv.y; acc[r][2].z += w2 * mv.z; acc[r][2].w += w2 * mv.w;
        acc[r][3].x += w3 * mv.x; acc[r][3].y += w3 * mv.y; acc[r][3].z += w3 * mv.z; acc[r][3].w += w3 * mv.w;
      }
    }
  }
  // write partials: part[sc][r][b][m]
#pragma unroll
  for (int r = 0; r < 4; r++) {
    float* pp = part + ((size_t)(sc * 4 + r)) * 4096;
#pragma unroll
    for (int jb = 0; jb < 4; jb++)
      *((float4*)&pp[(bq * 4 + jb) * 64 + mq * 4]) = acc[r][jb];
  }
  // GS_r
#pragma unroll
  for (int r = 0; r < 4; r++) {
    const float w = waveReduceSum(gs_acc[r]);
    if (lane == 0) wsum[r][wave] = w;
  }
  __syncthreads();
  if (t < 4) atomicAdd(&GS[1 + t], wsum[t][0] + wsum[t][1] + wsum[t][2] + wsum[t][3]);
}

// ---------------------------------------------------------------------------
// K7: reduce 512 superchunk partials and normalize by GS_r. grid 64, block 256.
// ---------------------------------------------------------------------------
__global__ __launch_bounds__(256) void finalize_kernel(
    const float* __restrict__ part, const float* __restrict__ GS,
    float* __restrict__ out)
{
  const int idx = blockIdx.x * 256 + threadIdx.x;  // 0..16383
  const int b = idx >> 8, rm = idx & 255, r = rm >> 6, m = rm & 63;
  const int off = r * 4096 + b * 64 + m;
  float sum = 0.f;
#pragma unroll 8
  for (int scq = 0; scq < 512; scq++) sum += part[(size_t)scq * 16384 + off];
  out[idx] = sum / (GS[1 + r] + 1e-5f);
}

// ---------------------------------------------------------------------------
extern "C" void kernel_launch(void* const* d_in, const int* in_sizes, int n_in,
                              void* d_out, int out_size, void* d_ws, size_t ws_size,
                              hipStream_t stream) {
  (void)in_sizes; (void)n_in; (void)out_size; (void)ws_size;
  const float* h_t    = (const float*)d_in[0];
  const float* ww     = (const float*)d_in[1];
  const float* wr     = (const float*)d_in[2];
  const float* memory = (const float*)d_in[3];
  const float* key_w  = (const float*)d_in[4];
  const float* key_b  = (const float*)d_in[5];
  const float* beta_w = (const float*)d_in[6];
  const float* beta_b = (const float*)d_in[7];
  const float* gate_w = (const float*)d_in[8];
  const float* gate_b = (const float*)d_in[9];
  const float* shift_w = (const float*)d_in[10];
  const float* shift_b = (const float*)d_in[11];
  const float* gamma_w = (const float*)d_in[12];
  const float* gamma_b = (const float*)d_in[13];
  const float* erase_w = (const float*)d_in[14];
  const float* erase_b = (const float*)d_in[15];
  const float* add_w   = (const float*)d_in[16];
  const float* add_b   = (const float*)d_in[17];
  const int*   bank    = (const int*)d_in[18];

  float* ws = (float*)d_ws;
  // Layout (floats):
  //   E1   [0,        4194304)
  //   m1   [4194304,  8388608)
  //   part [8388608, 16777216)   512 sc x 4 r x 64 b x 64 m  (33.5 MB)
  //   E0   [12582912,16777216)   aliases part's 2nd half; E0 dead before read
  //   smallb at 16777216
  float* E1   = ws;
  float* m1   = ws + 4194304;
  float* part = ws + 8388608;
  float* E0   = ws + 12582912;
  float* smallb = ws + 16777216;
  float* kn    = smallb;             // 4096
  float* e_v   = smallb + 4096;      // 4096
  float* a_v   = smallb + 8192;      // 4096
  float* beta  = smallb + 12288;     // 64
  float* g     = smallb + 12352;     // 64
  float* gam   = smallb + 12416;     // 64
  float* s     = smallb + 12480;     // 192
  float* RS0   = smallb + 12672;     // 64
  float* RS1   = smallb + 12736;     // 64
  float* GS    = smallb + 12800;     // 5: [0]=GS0, [1..4]=GS_r

  prep_kernel<<<64, 256, 0, stream>>>(h_t, key_w, key_b, beta_w, beta_b,
                                      gate_w, gate_b, shift_w, shift_b,
                                      gamma_w, gamma_b, erase_w, erase_b,
                                      add_w, add_b,
                                      kn, e_v, a_v, beta, g, gam, s, RS0, RS1, GS);
  content_kernel<<<512, 256, 0, stream>>>(memory, bank, kn, beta, E0, RS0);
  gs0_kernel<<<dim3(32, 64), 256, 0, stream>>>(E0, ww, RS0, g, gam, s, GS);
  apply_write_kernel<<<1024, 256, 0, stream>>>(E0, ww, RS0, g, gam, s, GS,
                                               e_v, a_v, memory, bank, m1);
  content_kernel<<<512, 256, 0, stream>>>(m1, nullptr, kn, beta, E1, RS1);
  read_kernel<<<512, 256, 0, stream>>>(E1, wr, RS1, g, gam, s, m1, part, GS);
  finalize_kernel<<<64, 256, 0, stream>>>(part, GS, (float*)d_out);
}

// Round 5
// 583.633 us; speedup vs baseline: 1.3706x; 1.1224x over previous
//
#include <hip/hip_runtime.h>

#define NN 65536
#define BB 64
#define HH 1024
#define MM 64
#define RR 4

__device__ __forceinline__ float waveReduceSum(float v) {
#pragma unroll
  for (int off = 32; off > 0; off >>= 1) v += __shfl_xor(v, off, 64);
  return v;
}

// fast pow for positive base: wt^p = exp(p * log(wt))
__device__ __forceinline__ float fastPow(float wt, float p) {
  return __expf(p * __logf(wt));
}

// shifted, gated interpolation weight at n (lane == n % 64), divergent-halo
// version (used by gs0 / apply_write where it's not the bottleneck).
__device__ __forceinline__ float shifted_wg(
    const float* __restrict__ Eb, const float* __restrict__ wb, int n,
    float gb, float rinv, float s0, float s1, float s2) {
  const int lane = threadIdx.x & 63;
  const float omg = 1.f - gb;
  const float wgc = gb * Eb[n] * rinv + omg * wb[n];
  float wgm = __shfl_up(wgc, 1, 64);
  float wgp = __shfl_down(wgc, 1, 64);
  if (lane == 0)  wgm = (n > 0)      ? (gb * Eb[n - 1] * rinv + omg * wb[n - 1]) : 0.f;
  if (lane == 63) wgp = (n < NN - 1) ? (gb * Eb[n + 1] * rinv + omg * wb[n + 1]) : 0.f;
  return s0 * wgm + s1 * wgc + s2 * wgp;
}

// ---------------------------------------------------------------------------
// K1: per-batch head parameters from h_t. grid 64, block 256.
// ---------------------------------------------------------------------------
__global__ __launch_bounds__(256) void prep_kernel(
    const float* __restrict__ h_t,
    const float* __restrict__ key_w, const float* __restrict__ key_b,
    const float* __restrict__ beta_w, const float* __restrict__ beta_b,
    const float* __restrict__ gate_w, const float* __restrict__ gate_b,
    const float* __restrict__ shift_w, const float* __restrict__ shift_b,
    const float* __restrict__ gamma_w, const float* __restrict__ gamma_b,
    const float* __restrict__ erase_w, const float* __restrict__ erase_b,
    const float* __restrict__ add_w, const float* __restrict__ add_b,
    float* __restrict__ kn, float* __restrict__ e_v, float* __restrict__ a_v,
    float* __restrict__ beta, float* __restrict__ g, float* __restrict__ gamma_,
    float* __restrict__ s,
    float* __restrict__ RS0, float* __restrict__ RS1, float* __restrict__ GS)
{
  const int b = blockIdx.x;
  const int t = threadIdx.x;
  __shared__ float h_sh[HH];
  __shared__ float part3[3][64][5];
  __shared__ float k_sh[64];
#pragma unroll
  for (int i = 0; i < 4; i++) h_sh[t + 256 * i] = h_t[b * HH + t + 256 * i];
  __syncthreads();

  const int c = t & 63, grp = t >> 6;
  const int h0 = grp * 256;
  float dk = 0.f, de = 0.f, da = 0.f;
#pragma unroll 4
  for (int i = 0; i < 256; i++) {
    const float hv = h_sh[h0 + i];
    dk += hv * key_w[(h0 + i) * 64 + c];
    de += hv * erase_w[(h0 + i) * 64 + c];
    da += hv * add_w[(h0 + i) * 64 + c];
  }
  part3[0][c][grp] = dk;
  part3[1][c][grp] = de;
  part3[2][c][grp] = da;
  __syncthreads();

  if (t < 64) {
    const float v = part3[0][t][0] + part3[0][t][1] + part3[0][t][2] + part3[0][t][3];
    k_sh[t] = fminf(fmaxf(v + key_b[t], 0.f), 1.f);
  } else if (t < 128) {
    const int m = t - 64;
    const float v = part3[1][m][0] + part3[1][m][1] + part3[1][m][2] + part3[1][m][3];
    e_v[b * 64 + m] = fminf(fmaxf(v + erase_b[m], 0.f), 1.f);
  } else if (t < 192) {
    const int m = t - 128;
    const float v = part3[2][m][0] + part3[2][m][1] + part3[2][m][2] + part3[2][m][3];
    a_v[b * 64 + m] = fminf(fmaxf(v + add_b[m], 0.f), 1.f);  // relu+clip01 == clip01
  } else {
    const int lane = t - 192;
    float outs[6];
#pragma unroll 1
    for (int o = 0; o < 6; o++) {
      float d = 0.f;
      if (o < 3) {
        const float* W = (o == 0) ? beta_w : ((o == 1) ? gate_w : gamma_w);
        for (int hh = lane; hh < HH; hh += 64) d += h_sh[hh] * W[hh];
      } else {
        const int j = o - 3;
        for (int hh = lane; hh < HH; hh += 64) d += h_sh[hh] * shift_w[hh * 3 + j];
      }
      outs[o] = waveReduceSum(d);
    }
    if (lane == 0) {
      beta[b]   = fmaxf(outs[0] + beta_b[0], 0.f);
      g[b]      = fminf(fmaxf(outs[1] + gate_b[0], 0.f), 1.f);
      gamma_[b] = 1.0f + fmaxf(outs[2] + gamma_b[0], 0.f);
      const float l0 = outs[3] + shift_b[0];
      const float l1 = outs[4] + shift_b[1];
      const float l2 = outs[5] + shift_b[2];
      const float mx = fmaxf(l0, fmaxf(l1, l2));
      const float e0 = __expf(l0 - mx), e1 = __expf(l1 - mx), e2 = __expf(l2 - mx);
      const float inv = 1.f / (e0 + e1 + e2);
      s[b * 3 + 0] = e0 * inv; s[b * 3 + 1] = e1 * inv; s[b * 3 + 2] = e2 * inv;
    }
  }
  __syncthreads();
  if (t < 64) {
    float ss = 0.f;
    for (int j = 0; j < 64; j++) ss += k_sh[j] * k_sh[j];
    kn[b * 64 + t] = k_sh[t] / (sqrtf(ss) + 1e-8f);
  }
  if (b == 0) {
    if (t < 64) { RS0[t] = 0.f; RS1[t] = 0.f; }
    if (t < 5) GS[t] = 0.f;
  }
}

// ---------------------------------------------------------------------------
// K2 / K5: content addressing. grid (512 n-chunks of 128, 2 b-halves), 256 t.
// Rows in registers; kn/beta via wave-uniform scalar loads (readfirstlane).
// ---------------------------------------------------------------------------
__global__ __launch_bounds__(256) void content_kernel(
    const float* __restrict__ mem, const int* __restrict__ bank,
    const float* __restrict__ kn, const float* __restrict__ beta,
    float* __restrict__ E, float* __restrict__ RS)
{
  const float* Mrow = mem + (bank ? ((size_t)(*bank) * (size_t)NN * MM) : (size_t)0);
  const int t = threadIdx.x;
  const int nl = t & 127;
  const int n = blockIdx.x * 128 + nl;
  const int bgrp = t >> 7;                 // 0/1: which 16-b group
  const int nhalf = (t >> 6) & 1;          // which 64-n half
  const int lane = t & 63;
  const int b0 = blockIdx.y * 32 + bgrp * 16;

  float4 row[16];
  const float4* rp = (const float4*)(Mrow + (size_t)n * MM);
#pragma unroll
  for (int q = 0; q < 16; q++) row[q] = rp[q];
  float ss = 0.f;
#pragma unroll
  for (int q = 0; q < 16; q++)
    ss += row[q].x * row[q].x + row[q].y * row[q].y + row[q].z * row[q].z + row[q].w * row[q].w;
  const float rinv = 1.0f / (sqrtf(ss) + 1e-8f);

  __shared__ float accs[32][2];
  for (int i = 0; i < 16; i++) {
    const int rb = __builtin_amdgcn_readfirstlane(b0 + i);
    const float4* kp = (const float4*)(kn + rb * 64);
    float dot = 0.f;
#pragma unroll
    for (int q = 0; q < 16; q++) {
      const float4 kq = kp[q];
      dot += kq.x * row[q].x + kq.y * row[q].y + kq.z * row[q].z + kq.w * row[q].w;
    }
    const float e = __expf(beta[rb] * dot * rinv);
    E[(size_t)rb * NN + n] = e;
    const float r = waveReduceSum(e);
    if (lane == 0) accs[bgrp * 16 + i][nhalf] = r;
  }
  __syncthreads();
  if (t < 32) atomicAdd(&RS[blockIdx.y * 32 + t], accs[t][0] + accs[t][1]);
}

// ---------------------------------------------------------------------------
// K3: global sum of w_pow for the write head (GS0). grid (32, 64), block 256.
// ---------------------------------------------------------------------------
__global__ __launch_bounds__(256, 2) void gs0_kernel(
    const float* __restrict__ E0, const float* __restrict__ ww,
    const float* __restrict__ RS0, const float* __restrict__ g,
    const float* __restrict__ gamma_, const float* __restrict__ s,
    float* __restrict__ GS)
{
  const int b = blockIdx.y;
  const float gb = g[b], gmb = gamma_[b];
  const float s0 = s[b * 3], s1 = s[b * 3 + 1], s2 = s[b * 3 + 2];
  const float rinv = 1.0f / RS0[b];
  const float* Eb = E0 + (size_t)b * NN;
  const float* wb = ww + (size_t)b * NN;
  const int base = blockIdx.x * 2048;
  float acc = 0.f;
  for (int k = 0; k < 8; k++) {
    const int n = base + k * 256 + threadIdx.x;
    const float wt = shifted_wg(Eb, wb, n, gb, rinv, s0, s1, s2);
    acc += fastPow(wt, gmb);
  }
  __shared__ float wsum[4];
  const float w = waveReduceSum(acc);
  if ((threadIdx.x & 63) == 0) wsum[threadIdx.x >> 6] = w;
  __syncthreads();
  if (threadIdx.x == 0) atomicAdd(&GS[0], wsum[0] + wsum[1] + wsum[2] + wsum[3]);
}

// ---------------------------------------------------------------------------
// K4: apply write head. grid 1024 x 128 threads. thread = (n = lane, m-half =
// wave). er/ad[32] in regs; e/a via wave-uniform scalar loads. No LDS.
// ---------------------------------------------------------------------------
__global__ __launch_bounds__(128, 2) void apply_write_kernel(
    const float* __restrict__ E0, const float* __restrict__ ww,
    const float* __restrict__ RS0, const float* __restrict__ g,
    const float* __restrict__ gamma_, const float* __restrict__ s,
    const float* __restrict__ GS,
    const float* __restrict__ e_v, const float* __restrict__ a_v,
    const float* __restrict__ memory, const int* __restrict__ bank,
    float* __restrict__ m1)
{
  const int t = threadIdx.x;
  const int lane = t & 63;
  const int rmh = __builtin_amdgcn_readfirstlane(t >> 6);  // m-half, 0/1
  const int n = blockIdx.x * 64 + lane;
  const float invGS = 1.0f / (GS[0] + 1e-5f);
  float er[32], ad[32];
#pragma unroll
  for (int j = 0; j < 32; j++) { er[j] = 0.f; ad[j] = 0.f; }
#pragma unroll 2
  for (int b = 0; b < 64; b++) {
    const float gb = g[b], gmb = gamma_[b];
    const float s0 = s[b * 3], s1 = s[b * 3 + 1], s2 = s[b * 3 + 2];
    const float rinv = 1.0f / RS0[b];
    const float wt = shifted_wg(E0 + (size_t)b * NN, ww + (size_t)b * NN, n,
                                gb, rinv, s0, s1, s2);
    const float c = fastPow(wt, gmb) * invGS;
    const float4* e4 = (const float4*)(e_v + b * 64 + rmh * 32);
    const float4* a4 = (const float4*)(a_v + b * 64 + rmh * 32);
#pragma unroll
    for (int j = 0; j < 8; j++) {
      const float4 ev = e4[j], av = a4[j];
      er[j * 4 + 0] += c * ev.x; er[j * 4 + 1] += c * ev.y;
      er[j * 4 + 2] += c * ev.z; er[j * 4 + 3] += c * ev.w;
      ad[j * 4 + 0] += c * av.x; ad[j * 4 + 1] += c * av.y;
      ad[j * 4 + 2] += c * av.z; ad[j * 4 + 3] += c * av.w;
    }
  }
  const float* M0 = memory + (size_t)(*bank) * (size_t)NN * MM;
  const float4* m0p = (const float4*)(M0 + (size_t)n * MM + rmh * 32);
  float4* m1p = (float4*)(m1 + (size_t)n * MM + rmh * 32);
#pragma unroll
  for (int j = 0; j < 8; j++) {
    const float4 mv = m0p[j];
    float4 o;
    o.x = mv.x * (1.f - er[j * 4 + 0]) + ad[j * 4 + 0];
    o.y = mv.y * (1.f - er[j * 4 + 1]) + ad[j * 4 + 1];
    o.z = mv.z * (1.f - er[j * 4 + 2]) + ad[j * 4 + 2];
    o.w = mv.w * (1.f - er[j * 4 + 3]) + ad[j * 4 + 3];
    m1p[j] = o;
  }
}

// ---------------------------------------------------------------------------
// K6: read heads. grid 512 (128-n), block 512 (8 waves). Wave-pair half h
// owns r = 2h, 2h+1 (own w_sh, shared m1_sh). Per (tile, r): batch 32+1
// global loads into regs (halo via lane-specialized load + shfl), barrier,
// compute w_pow -> w_sh, barrier, 4x4 register-tile accumulate.
// ---------------------------------------------------------------------------
__global__ __launch_bounds__(512, 4) void read_kernel(
    const float* __restrict__ E1, const float* __restrict__ wr,
    const float* __restrict__ RS1, const float* __restrict__ g,
    const float* __restrict__ gamma_, const float* __restrict__ sv,
    const float* __restrict__ m1,
    float* __restrict__ part, float* __restrict__ GS)
{
  const int sc = blockIdx.x;       // 128-n superchunk
  const int t = threadIdx.x;       // 0..511
  const int half = t >> 8;         // r-pair
  const int th = t & 255;
  const int lane = t & 63;
  const int rwq = __builtin_amdgcn_readfirstlane((t >> 6) & 3);  // wave-in-half
  const int mq = th & 15, bq = th >> 4;
  __shared__ float m1_sh[64 * 68];
  __shared__ float w_sh[2][64 * 66];
  __shared__ float cgr[64], comg[64], cs0[64], cs1[64], cs2[64], cgm[64];
  __shared__ float wsum[4][4];
  if (t < 64) {
    const float gb = g[t];
    cgr[t] = gb / RS1[t];
    comg[t] = 1.f - gb;
    cs0[t] = sv[t * 3]; cs1[t] = sv[t * 3 + 1]; cs2[t] = sv[t * 3 + 2];
    cgm[t] = gamma_[t];
  }
  float4 acc[2][4];
#pragma unroll
  for (int rl = 0; rl < 2; rl++)
#pragma unroll
    for (int j = 0; j < 4; j++) acc[rl][j] = make_float4(0.f, 0.f, 0.f, 0.f);
  float gs_acc[2] = {0.f, 0.f};

  for (int tile = 0; tile < 2; tile++) {
    const int n0 = sc * 128 + tile * 64;
    const int n = n0 + lane;
    __syncthreads();  // previous tile fully consumed
    // stage m1 tile [64n x 64m] -> m1_sh (pad 68)
#pragma unroll
    for (int rep = 0; rep < 2; rep++) {
      const int idx = rep * 512 + t;
      const int nl = idx >> 4, mc = idx & 15;
      const float4 v = ((const float4*)(m1 + (size_t)(n0 + nl) * MM))[mc];
      *((float4*)&m1_sh[nl * 68 + mc * 4]) = v;
    }
    for (int rl = 0; rl < 2; rl++) {
      const int r = half * 2 + rl;
      const float* wrr = wr + (size_t)r * BB * NN;
      // ---- batched loads for this phase (issued before the barrier) ----
      float eB[16], wB[16];
#pragma unroll
      for (int i = 0; i < 16; i++) {
        const int b = rwq * 16 + i;
        eB[i] = E1[(size_t)b * NN + n];
        wB[i] = wrr[(size_t)b * NN + n];
      }
      // halo vector: lanes 0-15 E-left(i=lane), 16-31 w-left, 32-47 E-right,
      // 48-63 w-right
      float hv = 0.f;
      {
        const int side = lane >> 5;
        const int isE = ((lane >> 4) & 1) == 0;
        const int hb = rwq * 16 + (lane & 15);
        const long hn = side ? (long)n0 + 64 : (long)n0 - 1;
        if (hn >= 0 && hn < (long)NN)
          hv = isE ? E1[(size_t)hb * NN + hn] : wrr[(size_t)hb * NN + hn];
      }
      __syncthreads();  // w_sh free (prev accumulate done); m1_sh staged
      // ---- compute w_pow tile into w_sh[half][b][66] ----
#pragma unroll
      for (int i = 0; i < 16; i++) {
        const int b = rwq * 16 + i;
        const float gbr = cgr[b], omg = comg[b];
        const float wgc = gbr * eB[i] + omg * wB[i];
        float wgm = __shfl_up(wgc, 1, 64);
        float wgp = __shfl_down(wgc, 1, 64);
        const float wgmH = gbr * __shfl(hv, i, 64) + omg * __shfl(hv, 16 + i, 64);
        const float wgpH = gbr * __shfl(hv, 32 + i, 64) + omg * __shfl(hv, 48 + i, 64);
        if (lane == 0) wgm = wgmH;
        if (lane == 63) wgp = wgpH;
        const float wt = cs0[b] * wgm + cs1[b] * wgc + cs2[b] * wgp;
        const float wp = fastPow(wt, cgm[b]);
        gs_acc[rl] += wp;
        w_sh[half][b * 66 + lane] = wp;
      }
      __syncthreads();
      // ---- accumulate: thread owns b = bq*4..+3, m = mq*4..+3 ----
#pragma unroll 4
      for (int nn = 0; nn < 64; nn++) {
        const float4 mv = *((const float4*)&m1_sh[nn * 68 + mq * 4]);
        const float w0 = w_sh[half][(bq * 4 + 0) * 66 + nn];
        const float w1 = w_sh[half][(bq * 4 + 1) * 66 + nn];
        const float w2 = w_sh[half][(bq * 4 + 2) * 66 + nn];
        const float w3 = w_sh[half][(bq * 4 + 3) * 66 + nn];
        acc[rl][0].x += w0 * mv.x; acc[rl][0].y += w0 * mv.y; acc[rl][0].z += w0 * mv.z; acc[rl][0].w += w0 * mv.w;
        acc[rl][1].x += w1 * mv.x; acc[rl][1].y += w1 * mv.y; acc[rl][1].z += w1 * mv.z; acc[rl][1].w += w1 * mv.w;
        acc[rl][2].x += w2 * mv.x; acc[rl][2].y += w2 * mv.y; acc[rl][2].z += w2 * mv.z; acc[rl][2].w += w2 * mv.w;
        acc[rl][3].x += w3 * mv.x; acc[rl][3].y += w3 * mv.y; acc[rl][3].z += w3 * mv.z; acc[rl][3].w += w3 * mv.w;
      }
    }
  }
  // write partials: part[sc][r][b][m]
#pragma unroll
  for (int rl = 0; rl < 2; rl++) {
    const int r = half * 2 + rl;
    float* pp = part + ((size_t)(sc * 4 + r)) * 4096;
#pragma unroll
    for (int j = 0; j < 4; j++)
      *((float4*)&pp[(bq * 4 + j) * 64 + mq * 4]) = acc[rl][j];
  }
  // GS_r
#pragma unroll
  for (int rl = 0; rl < 2; rl++) {
    const float w = waveReduceSum(gs_acc[rl]);
    if (lane == 0) wsum[half * 2 + rl][rwq] = w;
  }
  __syncthreads();
  if (t < 4) atomicAdd(&GS[1 + t], wsum[t][0] + wsum[t][1] + wsum[t][2] + wsum[t][3]);
}

// ---------------------------------------------------------------------------
// K7a: partial reduce of 512 superchunk partials: 16 groups of 32.
// grid (64, 16), block 256. part2[by][idx] (part2 aliases dead E1).
// ---------------------------------------------------------------------------
__global__ __launch_bounds__(256) void finalize1_kernel(
    const float* __restrict__ part, float* __restrict__ part2)
{
  const int idx = blockIdx.x * 256 + threadIdx.x;  // 0..16383
  const int b = idx >> 8, rm = idx & 255, r = rm >> 6, m = rm & 63;
  const int off = r * 4096 + b * 64 + m;
  const int s0 = blockIdx.y * 32;
  float sum = 0.f;
#pragma unroll 8
  for (int k = 0; k < 32; k++) sum += part[(size_t)(s0 + k) * 16384 + off];
  part2[blockIdx.y * 16384 + idx] = sum;
}

// ---------------------------------------------------------------------------
// K7b: final reduce + normalize. grid 64, block 256.
// ---------------------------------------------------------------------------
__global__ __launch_bounds__(256) void finalize2_kernel(
    const float* __restrict__ part2, const float* __restrict__ GS,
    float* __restrict__ out)
{
  const int idx = blockIdx.x * 256 + threadIdx.x;
  const int rm = idx & 255, r = rm >> 6;
  float sum = 0.f;
#pragma unroll
  for (int k = 0; k < 16; k++) sum += part2[k * 16384 + idx];
  out[idx] = sum / (GS[1 + r] + 1e-5f);
}

// ---------------------------------------------------------------------------
extern "C" void kernel_launch(void* const* d_in, const int* in_sizes, int n_in,
                              void* d_out, int out_size, void* d_ws, size_t ws_size,
                              hipStream_t stream) {
  (void)in_sizes; (void)n_in; (void)out_size; (void)ws_size;
  const float* h_t    = (const float*)d_in[0];
  const float* ww     = (const float*)d_in[1];
  const float* wr     = (const float*)d_in[2];
  const float* memory = (const float*)d_in[3];
  const float* key_w  = (const float*)d_in[4];
  const float* key_b  = (const float*)d_in[5];
  const float* beta_w = (const float*)d_in[6];
  const float* beta_b = (const float*)d_in[7];
  const float* gate_w = (const float*)d_in[8];
  const float* gate_b = (const float*)d_in[9];
  const float* shift_w = (const float*)d_in[10];
  const float* shift_b = (const float*)d_in[11];
  const float* gamma_w = (const float*)d_in[12];
  const float* gamma_b = (const float*)d_in[13];
  const float* erase_w = (const float*)d_in[14];
  const float* erase_b = (const float*)d_in[15];
  const float* add_w   = (const float*)d_in[16];
  const float* add_b   = (const float*)d_in[17];
  const int*   bank    = (const int*)d_in[18];

  float* ws = (float*)d_ws;
  // Layout (floats):
  //   E1    [0,        4194304)   (part2 aliases [0, 262144) after read)
  //   m1    [4194304,  8388608)
  //   part  [8388608, 16777216)   512 sc x 4 r x 64 b x 64 m
  //   E0    [12582912,16777216)   aliases part's 2nd half; dead before read
  //   smallb at 16777216
  float* E1    = ws;
  float* part2 = ws;               // aliases E1 (dead by finalize1)
  float* m1    = ws + 4194304;
  float* part  = ws + 8388608;
  float* E0    = ws + 12582912;
  float* smallb = ws + 16777216;
  float* kn    = smallb;             // 4096
  float* e_v   = smallb + 4096;      // 4096
  float* a_v   = smallb + 8192;      // 4096
  float* beta  = smallb + 12288;     // 64
  float* g     = smallb + 12352;     // 64
  float* gam   = smallb + 12416;     // 64
  float* s     = smallb + 12480;     // 192
  float* RS0   = smallb + 12672;     // 64
  float* RS1   = smallb + 12736;     // 64
  float* GS    = smallb + 12800;     // 5: [0]=GS0, [1..4]=GS_r

  prep_kernel<<<64, 256, 0, stream>>>(h_t, key_w, key_b, beta_w, beta_b,
                                      gate_w, gate_b, shift_w, shift_b,
                                      gamma_w, gamma_b, erase_w, erase_b,
                                      add_w, add_b,
                                      kn, e_v, a_v, beta, g, gam, s, RS0, RS1, GS);
  content_kernel<<<dim3(512, 2), 256, 0, stream>>>(memory, bank, kn, beta, E0, RS0);
  gs0_kernel<<<dim3(32, 64), 256, 0, stream>>>(E0, ww, RS0, g, gam, s, GS);
  apply_write_kernel<<<1024, 128, 0, stream>>>(E0, ww, RS0, g, gam, s, GS,
                                               e_v, a_v, memory, bank, m1);
  content_kernel<<<dim3(512, 2), 256, 0, stream>>>(m1, nullptr, kn, beta, E1, RS1);
  read_kernel<<<512, 512, 0, stream>>>(E1, wr, RS1, g, gam, s, m1, part, GS);
  finalize1_kernel<<<dim3(64, 16), 256, 0, stream>>>(part, part2);
  finalize2_kernel<<<64, 256, 0, stream>>>(part2, GS, (float*)d_out);
}